// Round 13
// baseline (173.761 us; speedup 1.0000x reference)
//
#include <hip/hip_runtime.h>
#include <cmath>

// CDF_origin_35407710388891: per-channel 1->3->3->3->1 pointwise MLP.
// tanh(f_i)==0 for given data => affine: out = a*v + b per channel.
// R10: A/B probe. Precompute (a,b)->ws (tiny kernel), then TWO half-streams:
//   A (ch 0-159):  1 float4/thread, plain loads/stores   (granularity test)
//   B (ch 160-319): 1 float4/thread, nontemporal ld/st   (+ cache-bypass test)
// rocprof reports each dispatch separately -> within-probe A/B.
// Input order: inputs, M0, b0, f0, M1, b1, f1, M2, b2, f2, M3, b3, stop_gradient

#define CCH 320
#define NN 65536
#define BLK 256
#define NV 16384                   // float4 per channel
#define BPC 64                     // blocks per channel (NV/BLK), 1 float4/thread
#define HC 160                     // channels per half
#define WS_STRIDE 64               // floats per channel in d_ws

typedef float vfloat4 __attribute__((ext_vector_type(4)));

// ws layout per channel (float index):
// [0]=a [1]=b [2]=gateflag(0/1)
// [4..6]=m0 [7..9]=B0 [10..12]=t0 [13..21]=m1 [22..24]=B1 [25..27]=t1
// [28..36]=m2 [37..39]=B2 [40..42]=t2 [43..45]=m3 [46]=B3

__device__ __forceinline__ float softplus_fast(float x) {
    return fmaxf(x, 0.0f) + __logf(1.0f + __expf(-fabsf(x)));
}
__device__ __forceinline__ float tanh_fast(float x) {
    return 1.0f - 2.0f / (__expf(2.0f * x) + 1.0f);
}

__global__ __launch_bounds__(BLK) void cdf_precompute_kernel(
    const float* __restrict__ M0, const float* __restrict__ b0, const float* __restrict__ f0,
    const float* __restrict__ M1, const float* __restrict__ b1, const float* __restrict__ f1,
    const float* __restrict__ M2, const float* __restrict__ b2, const float* __restrict__ f2,
    const float* __restrict__ M3, const float* __restrict__ b3,
    float* __restrict__ ws)
{
    const int c = blockIdx.x * BLK + threadIdx.x;
    if (c >= CCH) return;
    float* w = ws + (size_t)c * WS_STRIDE;

    float m0[3], B0[3], t0[3], m1[9], B1[3], t1[3], m2[9], B2[3], t2[3], m3[3];
#pragma unroll
    for (int i = 0; i < 3; ++i) {
        m0[i] = softplus_fast(M0[c*3+i]);
        B0[i] = b0[c*3+i];
        t0[i] = tanh_fast(f0[c*3+i]);
        B1[i] = b1[c*3+i];
        t1[i] = tanh_fast(f1[c*3+i]);
        B2[i] = b2[c*3+i];
        t2[i] = tanh_fast(f2[c*3+i]);
        m3[i] = softplus_fast(M3[c*3+i]);
    }
#pragma unroll
    for (int i = 0; i < 9; ++i) {
        m1[i] = softplus_fast(M1[c*9+i]);
        m2[i] = softplus_fast(M2[c*9+i]);
    }
    const float B3 = b3[c];

    const bool gated = t0[0] != 0.f || t0[1] != 0.f || t0[2] != 0.f ||
                       t1[0] != 0.f || t1[1] != 0.f || t1[2] != 0.f ||
                       t2[0] != 0.f || t2[1] != 0.f || t2[2] != 0.f;

    // affine composition in fp64 (same arithmetic as R6/R7 -> absmax passes)
    double w1[3], u1[3], w2[3], u2[3];
#pragma unroll
    for (int i = 0; i < 3; ++i) {
        w1[i] = (double)m1[i*3+0]*m0[0] + (double)m1[i*3+1]*m0[1] + (double)m1[i*3+2]*m0[2];
        u1[i] = (double)m1[i*3+0]*B0[0] + (double)m1[i*3+1]*B0[1] + (double)m1[i*3+2]*B0[2] + B1[i];
    }
#pragma unroll
    for (int i = 0; i < 3; ++i) {
        w2[i] = (double)m2[i*3+0]*w1[0] + (double)m2[i*3+1]*w1[1] + (double)m2[i*3+2]*w1[2];
        u2[i] = (double)m2[i*3+0]*u1[0] + (double)m2[i*3+1]*u1[1] + (double)m2[i*3+2]*u1[2] + B2[i];
    }
    w[0] = (float)((double)m3[0]*w2[0] + (double)m3[1]*w2[1] + (double)m3[2]*w2[2]);
    w[1] = (float)((double)m3[0]*u2[0] + (double)m3[1]*u2[1] + (double)m3[2]*u2[2] + B3);
    w[2] = gated ? 1.0f : 0.0f;
#pragma unroll
    for (int i = 0; i < 3; ++i) {
        w[4 + i]  = m0[i];  w[7 + i]  = B0[i];  w[10 + i] = t0[i];
        w[22 + i] = B1[i];  w[25 + i] = t1[i];
        w[37 + i] = B2[i];  w[40 + i] = t2[i];  w[43 + i] = m3[i];
    }
#pragma unroll
    for (int i = 0; i < 9; ++i) { w[13 + i] = m1[i]; w[28 + i] = m2[i]; }
    w[46] = B3;
}

template <bool NT>
__global__ __launch_bounds__(BLK) void cdf_stream_kernel(
    const float* __restrict__ in, const float* __restrict__ ws,
    float* __restrict__ out, int ch0)
{
    const int c = ch0 + (blockIdx.x >> 6);                 // block-uniform channel
    const int idx = (size_t)c * NV + (blockIdx.x & 63) * BLK + threadIdx.x;

    const vfloat4* __restrict__ inv  = reinterpret_cast<const vfloat4*>(in);
    vfloat4* __restrict__       outv = reinterpret_cast<vfloat4*>(out);
    const float* __restrict__ w = ws + (size_t)c * WS_STRIDE;

    const vfloat4 x = NT ? __builtin_nontemporal_load(&inv[idx]) : inv[idx];

    if (__builtin_expect(w[2] == 0.0f, 1)) {
        const float a = w[0], b = w[1];
        vfloat4 r;
        r.x = fmaf(a, x.x, b);
        r.y = fmaf(a, x.y, b);
        r.z = fmaf(a, x.z, b);
        r.w = fmaf(a, x.w, b);
        if (NT) __builtin_nontemporal_store(r, &outv[idx]);
        else    outv[idx] = r;
        return;
    }

    // ---- gated fallback (general data): full MLP per element ----
    float m0[3], B0[3], t0[3], m1[9], B1[3], t1[3], m2[9], B2[3], t2[3], m3[3];
#pragma unroll
    for (int i = 0; i < 3; ++i) {
        m0[i] = w[4 + i];  B0[i] = w[7 + i];  t0[i] = w[10 + i];
        B1[i] = w[22 + i]; t1[i] = w[25 + i];
        B2[i] = w[37 + i]; t2[i] = w[40 + i]; m3[i] = w[43 + i];
    }
#pragma unroll
    for (int i = 0; i < 9; ++i) { m1[i] = w[13 + i]; m2[i] = w[28 + i]; }
    const float B3 = w[46];

    float r[4] = {x.x, x.y, x.z, x.w};
#pragma unroll
    for (int k = 0; k < 4; ++k) {
        const float v = r[k];
        float h0[3], h1[3], h2[3];
#pragma unroll
        for (int j = 0; j < 3; ++j) {
            h0[j] = fmaf(m0[j], v, B0[j]);
            h0[j] = fmaf(t0[j], tanh_fast(h0[j]), h0[j]);
        }
#pragma unroll
        for (int j = 0; j < 3; ++j) {
            h1[j] = fmaf(m1[j*3+0], h0[0],
                    fmaf(m1[j*3+1], h0[1],
                    fmaf(m1[j*3+2], h0[2], B1[j])));
            h1[j] = fmaf(t1[j], tanh_fast(h1[j]), h1[j]);
        }
#pragma unroll
        for (int j = 0; j < 3; ++j) {
            h2[j] = fmaf(m2[j*3+0], h1[0],
                    fmaf(m2[j*3+1], h1[1],
                    fmaf(m2[j*3+2], h1[2], B2[j])));
            h2[j] = fmaf(t2[j], tanh_fast(h2[j]), h2[j]);
        }
        r[k] = fmaf(m3[0], h2[0], fmaf(m3[1], h2[1], fmaf(m3[2], h2[2], B3)));
    }
    vfloat4 o; o.x = r[0]; o.y = r[1]; o.z = r[2]; o.w = r[3];
    outv[idx] = o;
}

extern "C" void kernel_launch(void* const* d_in, const int* in_sizes, int n_in,
                              void* d_out, int out_size, void* d_ws, size_t ws_size,
                              hipStream_t stream) {
    const float* in = (const float*)d_in[0];
    const float* M0 = (const float*)d_in[1];
    const float* b0 = (const float*)d_in[2];
    const float* f0 = (const float*)d_in[3];
    const float* M1 = (const float*)d_in[4];
    const float* b1 = (const float*)d_in[5];
    const float* f1 = (const float*)d_in[6];
    const float* M2 = (const float*)d_in[7];
    const float* b2 = (const float*)d_in[8];
    const float* f2 = (const float*)d_in[9];
    const float* M3 = (const float*)d_in[10];
    const float* b3 = (const float*)d_in[11];
    float* out = (float*)d_out;
    float* ws  = (float*)d_ws;     // needs 320*64*4 = 80 KB

    cdf_precompute_kernel<<<dim3((CCH + BLK - 1) / BLK), BLK, 0, stream>>>(
        M0, b0, f0, M1, b1, f1, M2, b2, f2, M3, b3, ws);

    // A: channels [0,160), plain float4 loads/stores, 1 float4/thread
    cdf_stream_kernel<false><<<dim3(HC * BPC), BLK, 0, stream>>>(in, ws, out, 0);
    // B: channels [160,320), nontemporal loads/stores, 1 float4/thread
    cdf_stream_kernel<true><<<dim3(HC * BPC), BLK, 0, stream>>>(in, ws, out, HC);
}